// Round 1
// baseline (424.361 us; speedup 1.0000x reference)
//
#include <hip/hip_runtime.h>
#include <hip/hip_bf16.h>

// B=4, L=4096, D=1024, H=16, M=4, dk=64, n=1024. All-bf16 MFMA pipeline.
// R8: GEMM ported to the 256x256 8-phase schedule (T3+T4 counted vmcnt + T5
// setprio). 512 thr / 8 waves (2x4), BK=64, LDS 128KB double-buffered.
// Counted s_waitcnt vmcnt(4) once per K-tile (never 0 in steady state);
// raw s_barrier (no __syncthreads drain). XOR chunk swizzle kept from R7
// (bank-conflict-free, pre-swizzled global source for global_load_lds).
// attn/cvt/vtrans unchanged from R7.

typedef __attribute__((ext_vector_type(8))) short short8;
typedef __attribute__((ext_vector_type(8))) unsigned short ushort8v;
typedef __attribute__((ext_vector_type(4))) float floatx4;

__device__ __forceinline__ float b2f(unsigned short h) {
    union { unsigned int u; float f; } v; v.u = ((unsigned int)h) << 16; return v.f;
}
__device__ __forceinline__ unsigned short f2b(float f) {
    union { float f; unsigned int u; } v; v.f = f;
    unsigned int r = v.u + 0x7fffu + ((v.u >> 16) & 1u);
    return (unsigned short)(r >> 16);
}
__device__ __forceinline__ unsigned int fbits(float f) {
    union { float f; unsigned int u; } v; v.f = f; return v.u;
}
__device__ __forceinline__ void async_copy16(const unsigned short* g, unsigned short* l) {
    __builtin_amdgcn_global_load_lds((const __attribute__((address_space(1))) void*)g,
                                     (__attribute__((address_space(3))) void*)l, 16, 0, 0);
}

// ---------------- fp32 -> bf16 convert (x) ----------------
__global__ __launch_bounds__(256)
void cvt_kernel(const float* __restrict__ in, unsigned short* __restrict__ out, int n4) {
    int i = blockIdx.x * 256 + threadIdx.x;
    if (i >= n4) return;
    float4 v = ((const float4*)in)[i];
    ushort4 o;
    o.x = f2b(v.x); o.y = f2b(v.y); o.z = f2b(v.z); o.w = f2b(v.w);
    ((ushort4*)out)[i] = o;
}

// ---------------- W [K][N] fp32 -> Wt [N][K] bf16, all 4 weights in one grid ----------------
__global__ __launch_bounds__(256)
void cvt_w_t(const float* __restrict__ Wq, const float* __restrict__ Wk,
             const float* __restrict__ Wv, const float* __restrict__ Wo,
             unsigned short* __restrict__ Wt3, unsigned short* __restrict__ Wot, float s0) {
    __shared__ float tile[64][65];
    const int kt = blockIdx.x, nt = blockIdx.y, z = blockIdx.z;
    const float* W = (z == 0) ? Wq : (z == 1) ? Wk : (z == 2) ? Wv : Wo;
    unsigned short* Wt = (z < 3) ? (Wt3 + (size_t)z * 1048576) : Wot;
    const float sc = (z == 0) ? s0 : 1.0f;
    const int t = threadIdx.x;
    const int r = t >> 2, cg = t & 3;
    const float* src = W + (size_t)(kt * 64 + r) * 1024 + nt * 64 + cg * 16;
#pragma unroll
    for (int j = 0; j < 4; j++) {
        float4 v = *(const float4*)(src + j * 4);
        tile[r][cg * 16 + j * 4 + 0] = v.x;
        tile[r][cg * 16 + j * 4 + 1] = v.y;
        tile[r][cg * 16 + j * 4 + 2] = v.z;
        tile[r][cg * 16 + j * 4 + 3] = v.w;
    }
    __syncthreads();
    unsigned short* dst = Wt + (size_t)(nt * 64 + r) * 1024 + kt * 64 + cg * 16;
    ushort8v o0, o1;
#pragma unroll
    for (int j = 0; j < 8; j++) o0[j] = f2b(tile[cg * 16 + j][r] * sc);
#pragma unroll
    for (int j = 0; j < 8; j++) o1[j] = f2b(tile[cg * 16 + 8 + j][r] * sc);
    *(ushort8v*)(dst) = o0;
    *(ushort8v*)(dst + 8) = o1;
}

// ---------------- GEMM: C[M][N] = A[M][K] * Bt[N][K]^T + bias*bs ----------------
// BM=256, BN=256, BK=64; 512 threads = 8 waves (wr=w>>2 in {0,1}, wc=w&3).
// Per wave: 128x64 output = acc[8][4]; per K-tile 64 MFMA split into 4 phases
// of 16 (rt pairs); B-frags (8 ds_read_b128) loaded once per tile in phase 0.
// Stage stream (race-free, barrier-separated):
//   tile u p0: A-half0(u+1) -> As[buf^1]   (A of buf^1 read-complete at u-1 p3)
//   tile u p1: A-half1(u+1) -> As[buf^1]
//   tile u p2: B-half0(u+2) -> Bs[buf]     (B of buf read-complete at u p0)
//   tile u p3: B-half1(u+2) -> Bs[buf]
// vmcnt(4) at p3: B(u+2)'s 4 loads stay in flight; everything older (incl.
// A(u+1), B(u+1)) has landed before the next tile's reads. u>=14: vmcnt(0)
// since the youngest loads are then the ones needed next.
// Grid 768 (QKV, z=0..2) / 256 (out): xcd=id&7, q=id>>3, tileM=xcd*8+(q&7),
// rz=q>>3, tileN=rz&3, z=rz>>2.
#define GEMM_PHASE(RT0, RT1, STAGE_STMT, TAILWAIT)                                                            \
    {                                                                                                         \
        short8 a0k0 = *(const short8*)(Ab + (RT0) * 1024 + kx0);                                              \
        short8 a0k1 = *(const short8*)(Ab + (RT0) * 1024 + kx1);                                              \
        short8 a1k0 = *(const short8*)(Ab + (RT1) * 1024 + kx0);                                              \
        short8 a1k1 = *(const short8*)(Ab + (RT1) * 1024 + kx1);                                              \
        STAGE_STMT                                                                                            \
        __builtin_amdgcn_s_barrier();                                                                         \
        __builtin_amdgcn_s_setprio(1);                                                                        \
        _Pragma("unroll") for (int ct = 0; ct < 4; ct++)                                                      \
            acc[RT0][ct] = __builtin_amdgcn_mfma_f32_16x16x32_bf16(a0k0, bfr[ct][0], acc[RT0][ct], 0, 0, 0);  \
        _Pragma("unroll") for (int ct = 0; ct < 4; ct++)                                                      \
            acc[RT1][ct] = __builtin_amdgcn_mfma_f32_16x16x32_bf16(a1k0, bfr[ct][0], acc[RT1][ct], 0, 0, 0);  \
        _Pragma("unroll") for (int ct = 0; ct < 4; ct++)                                                      \
            acc[RT0][ct] = __builtin_amdgcn_mfma_f32_16x16x32_bf16(a0k1, bfr[ct][1], acc[RT0][ct], 0, 0, 0);  \
        _Pragma("unroll") for (int ct = 0; ct < 4; ct++)                                                      \
            acc[RT1][ct] = __builtin_amdgcn_mfma_f32_16x16x32_bf16(a1k1, bfr[ct][1], acc[RT1][ct], 0, 0, 0);  \
        __builtin_amdgcn_s_setprio(0);                                                                        \
        TAILWAIT                                                                                              \
        __builtin_amdgcn_s_barrier();                                                                         \
    }

template <bool F32OUT>
__global__ __launch_bounds__(512, 2)
void gemm_k(const unsigned short* __restrict__ A,
            const unsigned short* __restrict__ BtBase,
            const float* __restrict__ bias0,
            const float* __restrict__ bias1,
            const float* __restrict__ bias2,
            void* __restrict__ OutBase, float s0) {
    constexpr int K = 1024, N = 1024;
    __shared__ __align__(16) unsigned short As[2][16384];
    __shared__ __align__(16) unsigned short Bs[2][16384];
    const int id = blockIdx.x;
    const int xcd = id & 7;
    const int q = id >> 3;
    const int tileM = xcd * 8 + (q & 7);
    const int rz = q >> 3;
    const int tileN = rz & 3;
    const int z = rz >> 2;
    const unsigned short* Bt = BtBase + (size_t)z * (1024 * 1024);
    const float* bias = (z == 0) ? bias0 : (z == 1 ? bias1 : bias2);
    const float bs = (z == 0) ? s0 : 1.0f;
    const int tid = threadIdx.x, w = tid >> 6, lane = tid & 63;
    const int wr = w >> 2, wc = w & 3;
    const int g = lane >> 4, c = lane & 15;
    const int c7 = c & 7;
    const int r8 = lane >> 3, j8 = lane & 7;
    const int kcs = (j8 ^ r8) * 8;           // swizzled k-chunk this lane stages
    const int kx0 = ((g + 0) ^ c7) * 8;      // ds_read k-chunk, ks=0
    const int kx1 = ((g + 4) ^ c7) * 8;      // ds_read k-chunk, ks=1

    // wave w stages segments {h*16 + w*2, h*16 + w*2 + 1} of each 256-row tile
    const unsigned short* aBase = A  + (size_t)(tileM * 256 + w * 16 + r8) * K + kcs;
    const unsigned short* bBase = Bt + (size_t)(tileN * 256 + w * 16 + r8) * K + kcs;

    auto stageA = [&](int kt, int h, int nb) {
        async_copy16(aBase + (size_t)(h * 128) * K + kt * 64,     &As[nb][(h * 16 + w * 2 + 0) * 512]);
        async_copy16(aBase + (size_t)(h * 128 + 8) * K + kt * 64, &As[nb][(h * 16 + w * 2 + 1) * 512]);
    };
    auto stageB = [&](int kt, int h, int nb) {
        async_copy16(bBase + (size_t)(h * 128) * K + kt * 64,     &Bs[nb][(h * 16 + w * 2 + 0) * 512]);
        async_copy16(bBase + (size_t)(h * 128 + 8) * K + kt * 64, &Bs[nb][(h * 16 + w * 2 + 1) * 512]);
    };

    floatx4 acc[8][4];
#pragma unroll
    for (int i = 0; i < 8; i++)
#pragma unroll
        for (int jj = 0; jj < 4; jj++) acc[i][jj] = (floatx4){0.f, 0.f, 0.f, 0.f};

    // prologue: A(0), B(0), B(1); 12 loads; keep B(1)'s 4 in flight
    stageA(0, 0, 0); stageA(0, 1, 0);
    stageB(0, 0, 0); stageB(0, 1, 0);
    stageB(1, 0, 1); stageB(1, 1, 1);
    asm volatile("s_waitcnt vmcnt(4)" ::: "memory");
    __builtin_amdgcn_s_barrier();

    for (int u = 0; u < 16; ++u) {
        const int buf = u & 1;
        const unsigned short* Ab = &As[buf][(wr * 128 + c) * 64];
        const unsigned short* Bb = &Bs[buf][(wc * 64 + c) * 64];
        short8 bfr[4][2];
#pragma unroll
        for (int ct = 0; ct < 4; ct++) {
            bfr[ct][0] = *(const short8*)(Bb + ct * 1024 + kx0);
            bfr[ct][1] = *(const short8*)(Bb + ct * 1024 + kx1);
        }
        GEMM_PHASE(0, 1, if (u + 1 < 16) { stageA(u + 1, 0, buf ^ 1); }, ;)
        GEMM_PHASE(2, 3, if (u + 1 < 16) { stageA(u + 1, 1, buf ^ 1); }, ;)
        GEMM_PHASE(4, 5, if (u + 2 < 16) { stageB(u + 2, 0, buf); }, ;)
        if (u < 14) {
            GEMM_PHASE(6, 7, { stageB(u + 2, 1, buf); },
                       asm volatile("s_waitcnt vmcnt(4)" ::: "memory");)
        } else {
            GEMM_PHASE(6, 7, ;, asm volatile("s_waitcnt vmcnt(0)" ::: "memory");)
        }
    }

#pragma unroll
    for (int ct = 0; ct < 4; ct++) {
        int col = tileN * 256 + wc * 64 + ct * 16 + c;
        float bvv = bias[col] * bs;
#pragma unroll
        for (int rt = 0; rt < 8; rt++) {
            int row0 = tileM * 256 + wr * 128 + rt * 16 + g * 4;
#pragma unroll
            for (int r = 0; r < 4; r++) {
                float v = acc[rt][ct][r] + bvv;
                if (F32OUT) {
                    ((float*)OutBase)[(size_t)(row0 + r) * N + col] = v;
                } else {
                    ((unsigned short*)OutBase)[(size_t)z * (16384ull * 1024ull) +
                                               (size_t)(row0 + r) * N + col] = f2b(v);
                }
            }
        }
    }
}

// ---------------- V transpose: v[B,L,D] -> Vt[slice=(b,h,m)][d=64][i=1024] ----------------
__global__ __launch_bounds__(256)
void vtrans(const unsigned short* __restrict__ V, unsigned short* __restrict__ Vt) {
    __shared__ unsigned short tile[64 * 72];
    const int it = blockIdx.x, s = blockIdx.y;
    const int m = s & 3, h = (s >> 2) & 15, b = s >> 6;
    const int tid = threadIdx.x;
    {
        int il = tid >> 2, cg = tid & 3;
        const unsigned short* gsrc =
            V + ((size_t)b * 4096 + m + 4 * (it * 64 + il)) * 1024 + h * 64 + cg * 16;
        *(ushort8v*)(tile + il * 72 + cg * 16) = *(const ushort8v*)gsrc;
        *(ushort8v*)(tile + il * 72 + cg * 16 + 8) = *(const ushort8v*)(gsrc + 8);
    }
    __syncthreads();
    {
        int dl = tid >> 2, ig = (tid & 3) * 16;
        ushort8v o0, o1;
#pragma unroll
        for (int j = 0; j < 8; j++) o0[j] = tile[(ig + j) * 72 + dl];
#pragma unroll
        for (int j = 0; j < 8; j++) o1[j] = tile[(ig + 8 + j) * 72 + dl];
        unsigned short* dst = Vt + (size_t)s * 65536 + (size_t)dl * 1024 + it * 64 + ig;
        *(ushort8v*)dst = o0;
        *(ushort8v*)(dst + 8) = o1;
    }
}

// ---------------- Attention ----------------
// 1-D grid 2048 blocks; decode xcd=id&7, q=id>>3, s=xcd*32+(q>>3), qt=q&7.
// Q frags live in registers (loaded once). S^T = K·Q^T; p=exp2(s) (scale folded
// into Wq); P packed to bf16 via v_perm_b32 into per-wave LDS; O = P·V with an
// extra all-ones B-frag MFMA accumulating l per-row in oacc-matched layout.
__global__ __launch_bounds__(256, 4)
void attn_k(const unsigned short* __restrict__ Qg,
            const unsigned short* __restrict__ Kg,
            const unsigned short* __restrict__ Vt,
            unsigned short* __restrict__ Og) {
    __shared__ __align__(16) unsigned short Ks[64 * 64];    // [kt4][ks][g][c][8]
    __shared__ __align__(16) unsigned short Vs[64 * 64];    // [dt][kc][g][c][8]
    __shared__ __align__(16) unsigned short Ps[4 * 2048];   // per-wave [rt*2+kc][g][c][8]

    const int id = blockIdx.x;
    const int xcd = id & 7;
    const int qq = id >> 3;
    const int s = xcd * 32 + (qq >> 3);
    const int qt = qq & 7;
    const int m = s & 3, h = (s >> 2) & 15, b = s >> 6;
    const int tid = threadIdx.x, w = tid >> 6, lane = tid & 63;
    const int g = lane >> 4, c = lane & 15;
    const size_t rowBase = (size_t)b * 4096;

    // Q fragments straight to registers (read-once data; 16B/lane)
    short8 qf[2][2];
#pragma unroll
    for (int rt = 0; rt < 2; rt++)
#pragma unroll
        for (int ks = 0; ks < 2; ks++)
            qf[rt][ks] = *(const short8*)(Qg +
                (rowBase + (size_t)(m + 4 * (qt * 128 + w * 32 + rt * 16 + c))) * 1024 +
                h * 64 + ks * 32 + g * 8);

    // strength-reduced staging pointers
    const unsigned short* kPtr =
        Kg + (rowBase + (size_t)(m + 4 * (w * 16 + c))) * 1024 + h * 64 + g * 8;
    const unsigned short* vPtr =
        Vt + (size_t)s * 65536 + (size_t)(w * 16 + c) * 1024 + g * 8;

    // all-ones B-fragment: l-column trick
    short8 ones;
#pragma unroll
    for (int j = 0; j < 8; j++) ones[j] = (short)0x3F80;   // bf16 1.0

    floatx4 oacc[2][4], lacc[2];
#pragma unroll
    for (int rt = 0; rt < 2; rt++) {
        lacc[rt] = (floatx4){0.f, 0.f, 0.f, 0.f};
#pragma unroll
        for (int dt = 0; dt < 4; dt++) oacc[rt][dt] = (floatx4){0.f, 0.f, 0.f, 0.f};
    }

    for (int kt = 0; kt < 16; ++kt) {
        __syncthreads();
        async_copy16(kPtr,      Ks + (w * 2 + 0) * 512);
        async_copy16(kPtr + 32, Ks + (w * 2 + 1) * 512);
        async_copy16(vPtr,      Vs + (w * 2 + 0) * 512);
        async_copy16(vPtr + 32, Vs + (w * 2 + 1) * 512);
        kPtr += 262144;   // 256 tokens * 1024 elems
        vPtr += 64;       // 64 keys along i-dim
        __syncthreads();

        // S^T[key][q] = K·Q^T : A=K (4 key-tiles), B=Q (2 q-tiles, regs)
        floatx4 sacc[4][2];
#pragma unroll
        for (int k4 = 0; k4 < 4; k4++)
#pragma unroll
            for (int rt = 0; rt < 2; rt++) sacc[k4][rt] = (floatx4){0.f, 0.f, 0.f, 0.f};
#pragma unroll
        for (int ks = 0; ks < 2; ks++) {
            short8 kf[4];
#pragma unroll
            for (int k4 = 0; k4 < 4; k4++)
                kf[k4] = *(const short8*)(Ks + (((k4 * 2 + ks) * 4 + g) * 16 + c) * 8);
#pragma unroll
            for (int k4 = 0; k4 < 4; k4++)
#pragma unroll
                for (int rt = 0; rt < 2; rt++)
                    sacc[k4][rt] = __builtin_amdgcn_mfma_f32_16x16x32_bf16(kf[k4], qf[rt][ks], sacc[k4][rt], 0, 0, 0);
        }

        // p = exp2(s), pack pairs via v_perm_b32, write b64 to per-wave Ps
#pragma unroll
        for (int k4 = 0; k4 < 4; k4++) {
            const int kc = k4 >> 1;
            const int gr = (k4 & 1) * 2 + (g >> 1);
            const int j0 = (g & 1) * 4;
#pragma unroll
            for (int rt = 0; rt < 2; rt++) {
                unsigned int u0 = fbits(__builtin_amdgcn_exp2f(sacc[k4][rt][0])) + 0x8000u;
                unsigned int u1 = fbits(__builtin_amdgcn_exp2f(sacc[k4][rt][1])) + 0x8000u;
                unsigned int u2 = fbits(__builtin_amdgcn_exp2f(sacc[k4][rt][2])) + 0x8000u;
                unsigned int u3 = fbits(__builtin_amdgcn_exp2f(sacc[k4][rt][3])) + 0x8000u;
                uint2 pk;
                pk.x = __builtin_amdgcn_perm(u1, u0, 0x07060302u);  // [e1.hi16 : e0.hi16]
                pk.y = __builtin_amdgcn_perm(u3, u2, 0x07060302u);
                *(uint2*)(Ps + w * 2048 + (((rt * 2 + kc) * 4 + gr) * 16 + c) * 8 + j0) = pk;
            }
        }

        // O += P·V ; l += P·1  (ones B-frag -> l lands oacc-aligned per row)
#pragma unroll
        for (int kc = 0; kc < 2; kc++) {
            short8 pf[2], vf[4];
#pragma unroll
            for (int rt = 0; rt < 2; rt++)
                pf[rt] = *(const short8*)(Ps + w * 2048 + (((rt * 2 + kc) * 4 + g) * 16 + c) * 8);
#pragma unroll
            for (int dt = 0; dt < 4; dt++)
                vf[dt] = *(const short8*)(Vs + (((dt * 2 + kc) * 4 + g) * 16 + c) * 8);
#pragma unroll
            for (int rt = 0; rt < 2; rt++) {
                lacc[rt] = __builtin_amdgcn_mfma_f32_16x16x32_bf16(pf[rt], ones, lacc[rt], 0, 0, 0);
#pragma unroll
                for (int dt = 0; dt < 4; dt++)
                    oacc[rt][dt] = __builtin_amdgcn_mfma_f32_16x16x32_bf16(pf[rt], vf[dt], oacc[rt][dt], 0, 0, 0);
            }
        }
    }

    // epilogue: l is already per-row in matching slots; normalize and scatter
#pragma unroll
    for (int rt = 0; rt < 2; rt++) {
#pragma unroll
        for (int r = 0; r < 4; r++) {
            float inv = 1.0f / lacc[rt][r];
            int token = m + 4 * (qt * 128 + w * 32 + rt * 16 + g * 4 + r);
            size_t rowOff = (rowBase + token) * 1024 + h * 64;
#pragma unroll
            for (int dt = 0; dt < 4; dt++)
                Og[rowOff + dt * 16 + c] = f2b(oacc[rt][dt][r] * inv);
        }
    }
}

extern "C" void kernel_launch(void* const* d_in, const int* in_sizes, int n_in,
                              void* d_out, int out_size, void* d_ws, size_t ws_size,
                              hipStream_t stream) {
    const float* x  = (const float*)d_in[0];
    const float* Wq = (const float*)d_in[1];
    const float* bq = (const float*)d_in[2];
    const float* Wk = (const float*)d_in[3];
    const float* bk = (const float*)d_in[4];
    const float* Wv = (const float*)d_in[5];
    const float* bv = (const float*)d_in[6];
    const float* Wo = (const float*)d_in[7];
    const float* bo = (const float*)d_in[8];

    const float SC = 0.18033688011112042f;  // (1/8) * log2(e), folded into Wq/bq

    char* ws = (char*)d_ws;
    const size_t SZ = 33554432;  // 32 MB = 16M bf16
    unsigned short* xb  = (unsigned short*)(ws);          // dead after QKV gemm
    unsigned short* Vtp = (unsigned short*)(ws);          // reuses xb region
    unsigned short* qb  = (unsigned short*)(ws + SZ);     // q,k,v contiguous
    unsigned short* ob  = (unsigned short*)(ws + 4 * SZ);
    unsigned short* Wt3 = (unsigned short*)(ws + 5 * SZ);
    unsigned short* Wot = Wt3 + 3ull * 1024 * 1024;

    cvt_kernel<<<16384, 256, 0, stream>>>(x, xb, 4194304);
    cvt_w_t<<<dim3(16, 16, 4), 256, 0, stream>>>(Wq, Wk, Wv, Wo, Wt3, Wot, SC);
    gemm_k<false><<<768, 512, 0, stream>>>(xb, Wt3, bq, bk, bv, qb, SC);
    vtrans<<<dim3(16, 256), 256, 0, stream>>>(qb + 2ull * 16777216ull, Vtp);
    attn_k<<<2048, 256, 0, stream>>>(qb, qb + 16777216ull, Vtp, ob);
    gemm_k<true><<<256, 512, 0, stream>>>(ob, Wot, bo, bo, bo, d_out, 1.0f);
}